// Round 2
// baseline (37.819 us; speedup 1.0000x reference)
//
#include <hip/hip_runtime.h>

#define N 6144
#define NTYPE 4
#define EPS_MIN 1.0f
#define EPS_MAX 5.0f
#define ALPHA 2.8f
#define R_CUTOFF 2.0f
#define R_ONSET 1.7f

constexpr int TILE_I = 256;             // threads per block = i-tile
constexpr int TILE_J = 64;              // j-tile per block
constexpr int NIB = N / TILE_I;         // 24
constexpr int NJB = N / TILE_J;         // 96
constexpr int NPART = NIB * NJB;        // 2304 partial sums

constexpr float RC2 = R_CUTOFF * R_CUTOFF;              // 4.0
constexpr float RO2 = R_ONSET * R_ONSET;                // 2.89
constexpr float INV_DENOM = 1.0f / ((RC2 - RO2) * (RC2 - RO2) * (RC2 - RO2));

__device__ __forceinline__ float block_reduce_256(float v) {
    __shared__ float ws[4];
    #pragma unroll
    for (int off = 32; off > 0; off >>= 1) v += __shfl_down(v, off);
    const int lane = threadIdx.x & 63;
    const int wid  = threadIdx.x >> 6;
    if (lane == 0) ws[wid] = v;
    __syncthreads();
    if (wid == 0) {
        v = (lane < 4) ? ws[lane] : 0.0f;
        #pragma unroll
        for (int off = 2; off > 0; off >>= 1) v += __shfl_down(v, off);
    }
    return v;  // valid in thread 0
}

// Pack per-particle derived data once:
//   A[i] = (x, y, z, radius)
//   B[i] = (s, c_last, type_bits, self_energy)
// self_energy is the diagonal (j==i) term the pair loop will also compute:
// dr2=0 -> r=1 (safe sqrt), sigma=2*rad, same-type eps = EPS_MAX*2s+EPS_MIN, cut(1)=1.
__global__ void __launch_bounds__(256)
prep_kernel(const float* __restrict__ pos,
            const float* __restrict__ celltype,
            const float* __restrict__ cadherin,
            const float* __restrict__ radius,
            float4* __restrict__ A, float4* __restrict__ B) {
    const int i = blockIdx.x * 256 + threadIdx.x;
    const float x = pos[i * 3 + 0];
    const float y = pos[i * 3 + 1];
    const float z = pos[i * 3 + 2];
    const float rad = radius[i];
    float s = 0.0f;
    int   t = 0;
    float best = -1.0f;
    #pragma unroll
    for (int k = 0; k < NTYPE; ++k) {
        const float c = celltype[i * NTYPE + k];
        s += c * cadherin[i * (NTYPE + 1) + k];
        if (c > best) { best = c; t = k; }
    }
    const float clast = cadherin[i * (NTYPE + 1) + NTYPE];

    // self term, written to match the pair-loop expression bit-for-bit
    const float r = 1.0f;
    const float sigma = rad + rad;
    const float e = expf(-ALPHA * (r - sigma));
    float eps = s + s;
    eps = EPS_MAX * eps + EPS_MIN;
    const float self = eps * (e * e - 2.0f * e);

    A[i] = make_float4(x, y, z, rad);
    B[i] = make_float4(s, clast, __int_as_float(t), self);
}

__global__ void __launch_bounds__(TILE_I)
pair_tile_kernel(const float4* __restrict__ A,
                 const float4* __restrict__ B,
                 float* __restrict__ partial) {
    __shared__ float4 sA[TILE_J];
    __shared__ float4 sB[TILE_J];

    const int ib  = blockIdx.x;
    const int jb  = blockIdx.y;
    const int i   = ib * TILE_I + threadIdx.x;
    const int jg0 = jb * TILE_J;

    if (threadIdx.x < TILE_J) {
        sA[threadIdx.x] = A[jg0 + threadIdx.x];
        sB[threadIdx.x] = B[jg0 + threadIdx.x];
    }
    const float4 ai = A[i];
    const float4 bi = B[i];
    const int   ti = __float_as_int(bi.z);
    const float si = bi.x;

    __syncthreads();

    float acc = 0.0f;
    #pragma unroll 8
    for (int jj = 0; jj < TILE_J; ++jj) {
        const float4 aj = sA[jj];
        const float dx = ai.x - aj.x;
        const float dy = ai.y - aj.y;
        const float dz = ai.z - aj.z;
        const float dr2 = dx * dx + dy * dy + dz * dz;
        if (dr2 < RC2) {                      // r >= cutoff contributes exactly 0
            const float r = (dr2 > 0.0f) ? sqrtf(dr2) : 1.0f;  // diagonal included; removed below
            const float4 bj = sB[jj];
            const float sigma = ai.w + aj.w;
            const float e = expf(-ALPHA * (r - sigma));
            const int   tj = __float_as_int(bj.z);
            float eps = (ti == tj) ? (si + bj.x) : (2.0f * bj.y);
            eps = EPS_MAX * eps + EPS_MIN;
            float cut;
            if (r < R_ONSET) {
                cut = 1.0f;
            } else {
                const float r2 = r * r;
                const float d  = RC2 - r2;
                cut = d * d * (RC2 + 2.0f * r2 - 3.0f * RO2) * INV_DENOM;
            }
            acc += eps * (e * e - 2.0f * e) * cut;
        }
    }

    // remove the self-interaction this block computed (exactly one j-block contains j==i)
    if ((unsigned)(i - jg0) < (unsigned)TILE_J) acc -= bi.w;

    const float bsum = block_reduce_256(acc);
    if (threadIdx.x == 0) partial[jb * NIB + ib] = bsum;
}

__global__ void __launch_bounds__(256)
final_reduce_kernel(const float* __restrict__ partial, float* __restrict__ out) {
    float acc = 0.0f;
    #pragma unroll
    for (int k = threadIdx.x; k < NPART; k += 256) acc += partial[k];
    const float total = block_reduce_256(acc);
    if (threadIdx.x == 0) out[0] = 0.5f * total;
}

extern "C" void kernel_launch(void* const* d_in, const int* in_sizes, int n_in,
                              void* d_out, int out_size, void* d_ws, size_t ws_size,
                              hipStream_t stream) {
    const float* pos      = (const float*)d_in[0];
    const float* celltype = (const float*)d_in[1];
    const float* cadherin = (const float*)d_in[2];
    const float* radius   = (const float*)d_in[3];
    float* out = (float*)d_out;

    // workspace layout: A[N] float4 | B[N] float4 | partial[NPART] float
    float4* A = (float4*)d_ws;
    float4* Bp = A + N;
    float*  partial = (float*)(Bp + N);

    prep_kernel<<<N / 256, 256, 0, stream>>>(pos, celltype, cadherin, radius, A, Bp);
    dim3 grid(NIB, NJB);
    pair_tile_kernel<<<grid, TILE_I, 0, stream>>>(A, Bp, partial);
    final_reduce_kernel<<<1, 256, 0, stream>>>(partial, out);
}

// Round 3
// 28.768 us; speedup vs baseline: 1.3146x; 1.3146x over previous
//
#include <hip/hip_runtime.h>

#define N 6144
#define NTYPE 4
#define EPS_MIN 1.0f
#define EPS_MAX 5.0f
#define ALPHA 2.8f
#define R_CUTOFF 2.0f
#define R_ONSET 1.7f

constexpr int TILE_I = 256;             // threads per block = i-tile
constexpr int TILE_J = 96;              // j-tile per block -> grid 24x64 = 1536 = 6 blocks/CU exactly
constexpr int NIB = N / TILE_I;         // 24
constexpr int NJB = N / TILE_J;         // 64
constexpr int NPART = NIB * NJB;        // 1536 partial sums

constexpr float RC2 = R_CUTOFF * R_CUTOFF;              // 4.0
constexpr float RO2 = R_ONSET * R_ONSET;                // 2.89
constexpr float INV_DENOM = 1.0f / ((RC2 - RO2) * (RC2 - RO2) * (RC2 - RO2));

__device__ __forceinline__ float block_reduce_256(float v) {
    __shared__ float ws[4];
    #pragma unroll
    for (int off = 32; off > 0; off >>= 1) v += __shfl_down(v, off);
    const int lane = threadIdx.x & 63;
    const int wid  = threadIdx.x >> 6;
    if (lane == 0) ws[wid] = v;
    __syncthreads();
    if (wid == 0) {
        v = (lane < 4) ? ws[lane] : 0.0f;
        #pragma unroll
        for (int off = 2; off > 0; off >>= 1) v += __shfl_down(v, off);
    }
    return v;  // valid in thread 0
}

// Derive per-particle packed data straight from the inputs (L2-hot, ~300 KB total):
//   a = (x, y, z, radius)   b = (s, c_last, type_bits, unused)
__device__ __forceinline__ void derive(int idx,
                                       const float* __restrict__ pos,
                                       const float* __restrict__ celltype,
                                       const float* __restrict__ cadherin,
                                       const float* __restrict__ radius,
                                       float4& a, float4& b) {
    const float x = pos[idx * 3 + 0];
    const float y = pos[idx * 3 + 1];
    const float z = pos[idx * 3 + 2];
    const float r = radius[idx];
    float s = 0.0f;
    int   t = 0;
    float best = -1.0f;
    #pragma unroll
    for (int k = 0; k < NTYPE; ++k) {
        const float c = celltype[idx * NTYPE + k];
        s += c * cadherin[idx * (NTYPE + 1) + k];
        if (c > best) { best = c; t = k; }
    }
    const float clast = cadherin[idx * (NTYPE + 1) + NTYPE];
    a = make_float4(x, y, z, r);
    b = make_float4(s, clast, __int_as_float(t), 0.0f);
}

__global__ void __launch_bounds__(TILE_I)
pair_kernel(const float* __restrict__ pos,
            const float* __restrict__ celltype,
            const float* __restrict__ cadherin,
            const float* __restrict__ radius,
            float* __restrict__ partial) {
    __shared__ float4 sA[TILE_J];
    __shared__ float4 sB[TILE_J];

    const int ib  = blockIdx.x;
    const int jb  = blockIdx.y;
    const int i   = ib * TILE_I + threadIdx.x;
    const int jg0 = jb * TILE_J;

    if (threadIdx.x < TILE_J) {
        float4 a, b;
        derive(jg0 + (int)threadIdx.x, pos, celltype, cadherin, radius, a, b);
        sA[threadIdx.x] = a;
        sB[threadIdx.x] = b;
    }
    float4 ai, bi;
    derive(i, pos, celltype, cadherin, radius, ai, bi);
    const int   ti = __float_as_int(bi.z);
    const float si = bi.x;

    __syncthreads();

    float acc = 0.0f;
    #pragma unroll 8
    for (int jj = 0; jj < TILE_J; ++jj) {
        const float4 aj = sA[jj];
        const float dx = ai.x - aj.x;
        const float dy = ai.y - aj.y;
        const float dz = ai.z - aj.z;
        const float dr2 = dx * dx + dy * dy + dz * dz;
        if (dr2 < RC2) {                      // r >= cutoff contributes exactly 0
            const float r = (dr2 > 0.0f) ? sqrtf(dr2) : 1.0f;  // diagonal included; removed below
            const float4 bj = sB[jj];
            const float sigma = ai.w + aj.w;
            const float e = __expf(-ALPHA * (r - sigma));
            const int   tj = __float_as_int(bj.z);
            float eps = (ti == tj) ? (si + bj.x) : (2.0f * bj.y);
            eps = EPS_MAX * eps + EPS_MIN;
            float cut;
            if (r < R_ONSET) {
                cut = 1.0f;
            } else {
                const float r2 = r * r;
                const float d  = RC2 - r2;
                cut = d * d * (RC2 + 2.0f * r2 - 3.0f * RO2) * INV_DENOM;
            }
            acc += eps * (e * e - 2.0f * e) * cut;
        }
    }

    // Subtract the self-interaction (computed above as the dr2==0 diagonal term):
    // r=1, cut=1, same-type eps; uses the same __expf so cancellation is ~exact.
    if ((unsigned)(i - jg0) < (unsigned)TILE_J) {
        const float sigma = ai.w + ai.w;
        const float e = __expf(-ALPHA * (1.0f - sigma));
        float eps = si + si;
        eps = EPS_MAX * eps + EPS_MIN;
        acc -= eps * (e * e - 2.0f * e);
    }

    const float bsum = block_reduce_256(acc);
    if (threadIdx.x == 0) partial[jb * NIB + ib] = bsum;
}

__global__ void __launch_bounds__(256)
final_reduce_kernel(const float* __restrict__ partial, float* __restrict__ out) {
    float acc = 0.0f;
    #pragma unroll
    for (int k = threadIdx.x; k < NPART; k += 256) acc += partial[k];
    const float total = block_reduce_256(acc);
    if (threadIdx.x == 0) out[0] = 0.5f * total;
}

extern "C" void kernel_launch(void* const* d_in, const int* in_sizes, int n_in,
                              void* d_out, int out_size, void* d_ws, size_t ws_size,
                              hipStream_t stream) {
    const float* pos      = (const float*)d_in[0];
    const float* celltype = (const float*)d_in[1];
    const float* cadherin = (const float*)d_in[2];
    const float* radius   = (const float*)d_in[3];
    float* out     = (float*)d_out;
    float* partial = (float*)d_ws;   // NPART floats

    dim3 grid(NIB, NJB);
    pair_kernel<<<grid, TILE_I, 0, stream>>>(pos, celltype, cadherin, radius, partial);
    final_reduce_kernel<<<1, 256, 0, stream>>>(partial, out);
}